// Round 2
// baseline (3114.677 us; speedup 1.0000x reference)
//
#include <hip/hip_runtime.h>
#include <hip/hip_bf16.h>

#define DM 512      // d_model
#define DI 1024     // d_inner
#define DSTATE 16
#define DTR 32      // dt_rank
#define NLAYER 8
#define BS 4
#define LL 256      // tokens per batch (F*NP)
#define MT 1024     // BS*LL total tokens
#define DPROJ 256

__device__ __forceinline__ float sigmoidf_(float x){ return 1.f/(1.f+__expf(-x)); }

// ---------------- patch embed: x[m,d] = sum_p ts[b, np*4+p] * ew[d,p] + eb[d]
__global__ __launch_bounds__(256) void embed_k(const float* __restrict__ ts,
    const float* __restrict__ ew, const float* __restrict__ eb, float* __restrict__ x){
  int idx = blockIdx.x*256 + threadIdx.x;     // MT*DM
  int m = idx >> 9, d = idx & 511;
  int b = m >> 8, np_ = m & 255;
  const float* t0 = ts + b*1024 + np_*4;
  float acc = eb[d];
  #pragma unroll
  for (int p=0;p<4;p++) acc = fmaf(t0[p], ew[d*4+p], acc);
  x[idx] = acc;
}

// ---------------- rmsnorm + write both normal and L-flipped copies
__global__ __launch_bounds__(256) void rmsnorm_k(const float* __restrict__ x,
    const float* __restrict__ nw, float* __restrict__ xn, float* __restrict__ xnf){
  int m = blockIdx.x, t = threadIdx.x;
  float2 v = *(const float2*)&x[(long)m*DM + t*2];
  float ss = v.x*v.x + v.y*v.y;
  ss += __shfl_down(ss,32); ss += __shfl_down(ss,16); ss += __shfl_down(ss,8);
  ss += __shfl_down(ss,4);  ss += __shfl_down(ss,2);  ss += __shfl_down(ss,1);
  __shared__ float ps[4];
  if ((t&63)==0) ps[t>>6] = ss;
  __syncthreads();
  float tot = ps[0]+ps[1]+ps[2]+ps[3];
  float rs = rsqrtf(tot*(1.f/DM) + 1e-5f);
  int b = m>>8, l = m&255, mf = (b<<8)+(255-l);
  float o0 = v.x*rs*nw[t*2], o1 = v.y*rs*nw[t*2+1];
  xn[(long)m*DM + t*2]  = o0; xn[(long)m*DM + t*2+1]  = o1;
  xnf[(long)mf*DM + t*2] = o0; xnf[(long)mf*DM + t*2+1] = o1;
}

// ---------------- generic C = A @ W^T   (A: MxK row-major w/ lda, W: NxK row-major)
// EPI: 0 = plain store, 1 = +bias, softplus, 2 = +bias, scatter to final output layout
template<int EPI>
__global__ __launch_bounds__(256) void gemm_nt(
    const float* __restrict__ A, int lda, long sA,
    const float* __restrict__ W, long sW,
    const float* __restrict__ bias, long sB,
    float* __restrict__ C, int ldc, long sC,
    int M, int N, int K)
{
  int z = blockIdx.z;
  A += z*sA; W += z*sW; C += z*sC;
  if (EPI==1) bias += z*sB;
  __shared__ float As[16][68];
  __shared__ float Ws[16][68];
  int tx = threadIdx.x, ty = threadIdx.y;
  int t = ty*16 + tx;
  int m0 = blockIdx.y*64, n0 = blockIdx.x*64;
  int lr = t>>2, lk = (t&3)*4;            // each thread loads a float4 of A and of W
  float acc[4][4] = {};
  for (int k0=0; k0<K; k0+=16){
    float4 va = *(const float4*)&A[(long)(m0+lr)*lda + k0 + lk];
    float4 vw = *(const float4*)&W[(long)(n0+lr)*K  + k0 + lk];
    As[lk][lr]=va.x; As[lk+1][lr]=va.y; As[lk+2][lr]=va.z; As[lk+3][lr]=va.w;
    Ws[lk][lr]=vw.x; Ws[lk+1][lr]=vw.y; Ws[lk+2][lr]=vw.z; Ws[lk+3][lr]=vw.w;
    __syncthreads();
    #pragma unroll
    for (int kk=0;kk<16;kk++){
      float a[4], bv[4];
      #pragma unroll
      for (int i=0;i<4;i++) a[i]  = As[kk][ty*4+i];
      #pragma unroll
      for (int j=0;j<4;j++) bv[j] = Ws[kk][tx*4+j];
      #pragma unroll
      for (int i=0;i<4;i++)
        #pragma unroll
        for (int j=0;j<4;j++)
          acc[i][j] = fmaf(a[i], bv[j], acc[i][j]);
    }
    __syncthreads();
  }
  #pragma unroll
  for (int i=0;i<4;i++){
    int m = m0 + ty*4 + i;
    #pragma unroll
    for (int j=0;j<4;j++){
      int n = n0 + tx*4 + j;
      float v = acc[i][j];
      if (EPI==1){ v += bias[n]; v = (v>20.f) ? v : log1pf(__expf(v)); }
      if (EPI==2){
        v += bias[n];
        int b = m>>8, np_ = m&255, p = n>>8, dp = n&255;
        C[((long)(b*1024 + np_*4 + p))*256 + dp] = v;
      } else {
        C[(long)m*ldc + n] = v;
      }
    }
  }
}

// ---------------- causal depthwise conv (taps=4) + bias + silu on u-half of xz
__global__ __launch_bounds__(256) void conv_silu_k(const float* __restrict__ xz,
    const float* __restrict__ cw, const float* __restrict__ cb, float* __restrict__ u){
  long idx = (long)blockIdx.x*256 + threadIdx.x;  // 2*MT*DI
  int e  = (int)(idx & (DI-1));
  int dm = (int)(idx >> 10);           // dir*MT + m
  int dir = dm >> 10;
  int m  = dm & (MT-1);
  int l  = m & (LL-1);
  const float* w = cw + ((long)dir*DI + e)*4;
  float acc = cb[dir*DI + e];
  const float* src = xz + (long)dm*2048 + e;   // u-half: cols [0,1024)
  #pragma unroll
  for (int j=0;j<4;j++){
    int ll = l - 3 + j;
    if (ll >= 0) acc = fmaf(w[j], src[(long)(j-3)*2048], acc);
  }
  u[idx] = acc * sigmoidf_(acc);
}

// ---------------- selective scan; thread = (e_local, n); fused gating epilogue
__global__ __launch_bounds__(256) void scan_k(
    const float* __restrict__ delta, const float* __restrict__ u,
    const float* __restrict__ xz, const float* __restrict__ xdbl,
    const float* __restrict__ A_log, const float* __restrict__ Dp,
    float* __restrict__ yg)
{
  int t = threadIdx.x;
  int n = t & 15, el = t >> 4;
  int ec = blockIdx.x, b = blockIdx.y, dir = blockIdx.z;
  int e = ec*16 + el;
  float Av = -__expf(A_log[((long)dir*DI + e)*16 + n]);
  float Dv = Dp[dir*DI + e];
  long mbase = (long)dir*MT + b*LL;
  const float* dp_ = delta + mbase*DI + e;
  const float* up_ = u     + mbase*DI + e;
  const float* zp_ = xz    + mbase*2048 + 1024 + e;
  const float* bc_ = xdbl  + mbase*64;
  float* yp_ = yg + mbase*DI + e;
  float h = 0.f;
  for (int l=0; l<LL; ++l){
    float dv = dp_[(long)l*DI];
    float uv = up_[(long)l*DI];
    float Bv = bc_[l*64 + 32 + n];
    float Cv = bc_[l*64 + 48 + n];
    float dA = __expf(dv*Av);
    h = fmaf(dA, h, dv*uv*Bv);
    float yc = h*Cv;
    yc += __shfl_xor(yc,1); yc += __shfl_xor(yc,2);
    yc += __shfl_xor(yc,4); yc += __shfl_xor(yc,8);
    if (n==0){
      float zv = zp_[(long)l*2048];
      yp_[(long)l*DI] = (yc + uv*Dv) * (zv * sigmoidf_(zv));
    }
  }
}

// ---------------- x = res + yf + flip(yb)
__global__ __launch_bounds__(256) void combine_k(float* __restrict__ x, const float* __restrict__ yout){
  int idx = blockIdx.x*256 + threadIdx.x;   // MT*DM/4
  int m = idx >> 7, c4 = idx & 127;
  int b = m>>8, l = m&255, mf = (b<<8)+(255-l);
  float4 r = ((const float4*)x)[idx];
  float4 f = ((const float4*)yout)[idx];
  float4 g = ((const float4*)(yout + (long)MT*DM))[(long)mf*128 + c4];
  r.x += f.x + g.x; r.y += f.y + g.y; r.z += f.z + g.z; r.w += f.w + g.w;
  ((float4*)x)[idx] = r;
}

extern "C" void kernel_launch(void* const* d_in, const int* in_sizes, int n_in,
                              void* d_out, int out_size, void* d_ws, size_t ws_size,
                              hipStream_t stream){
  const float* ts   = (const float*)d_in[0];
  // d_in[1] = mask (unused by reference)
  const float* ew   = (const float*)d_in[2];
  const float* eb   = (const float*)d_in[3];
  const float* nw   = (const float*)d_in[4];
  const float* inw  = (const float*)d_in[5];
  const float* cw   = (const float*)d_in[6];
  const float* cb   = (const float*)d_in[7];
  const float* xpw  = (const float*)d_in[8];
  const float* dtw  = (const float*)d_in[9];
  const float* dtb  = (const float*)d_in[10];
  const float* alog = (const float*)d_in[11];
  const float* dpp  = (const float*)d_in[12];
  const float* outw = (const float*)d_in[13];
  const float* pw   = (const float*)d_in[14];
  const float* pb   = (const float*)d_in[15];
  float* out = (float*)d_out;

  float* ws   = (float*)d_ws;
  float* x    = ws;                 // MT*DM              = 524288
  float* xn   = x    + 524288;      // 2*MT*DM (xn|xnf)   = 1048576
  float* xz   = xn   + 1048576;     // 2*MT*2048          = 4194304
  float* u    = xz   + 4194304;     // 2*MT*DI            = 2097152
  float* xdbl = u    + 2097152;     // 2*MT*64            = 131072
  float* delta= xdbl + 131072;      // 2*MT*DI            = 2097152
  float* yg   = delta+ 2097152;     // 2*MT*DI            = 2097152
  float* yout = yg   + 2097152;     // 2*MT*DM            = 1048576

  dim3 blk(256);
  dim3 gblk(16,16);

  embed_k<<<MT*DM/256, blk, 0, stream>>>(ts, ew, eb, x);

  for (int i=0;i<NLAYER;i++){
    rmsnorm_k<<<MT, blk, 0, stream>>>(x, nw + i*DM, xn, xn + 524288);
    // in_proj: (MT x 512) @ (2048 x 512)^T -> xz (MT x 2048), both dirs via z
    gemm_nt<0><<<dim3(2048/64, MT/64, 2), gblk, 0, stream>>>(
        xn, DM, 524288, inw + (long)i*2*2048*DM, (long)2048*DM,
        nullptr, 0, xz, 2048, (long)MT*2048, MT, 2048, DM);
    conv_silu_k<<<2*MT*DI/256, blk, 0, stream>>>(xz, cw + (long)i*2*DI*4, cb + i*2*DI, u);
    // x_dbl: (MT x 1024) @ (64 x 1024)^T
    gemm_nt<0><<<dim3(1, MT/64, 2), gblk, 0, stream>>>(
        u, DI, (long)MT*DI, xpw + (long)i*2*64*DI, (long)64*DI,
        nullptr, 0, xdbl, 64, (long)MT*64, MT, 64, DI);
    // delta = softplus(x_dbl[:, :32] @ (1024 x 32)^T + dt_b)
    gemm_nt<1><<<dim3(DI/64, MT/64, 2), gblk, 0, stream>>>(
        xdbl, 64, (long)MT*64, dtw + (long)i*2*DI*DTR, (long)DI*DTR,
        dtb + i*2*DI, DI, delta, DI, (long)MT*DI, MT, DI, DTR);
    scan_k<<<dim3(64, BS, 2), blk, 0, stream>>>(delta, u, xz, xdbl,
        alog + (long)i*2*DI*16, dpp + i*2*DI, yg);
    // out_proj: (MT x 1024) @ (512 x 1024)^T
    gemm_nt<0><<<dim3(DM/64, MT/64, 2), gblk, 0, stream>>>(
        yg, DI, (long)MT*DI, outw + (long)i*2*DM*DI, (long)DM*DI,
        nullptr, 0, yout, DM, (long)MT*DM, MT, DM, DI);
    combine_k<<<MT*DM/4/256, blk, 0, stream>>>(x, yout);
  }
  // final proj + bias + scatter into (B, S, F, D_PROJ) layout
  gemm_nt<2><<<dim3(1024/64, MT/64, 1), gblk, 0, stream>>>(
      x, DM, 0, pw, 0, pb, 0, out, 1024, 0, MT, 1024, DM);
}

// Round 3
// 2125.045 us; speedup vs baseline: 1.4657x; 1.4657x over previous
//
#include <hip/hip_runtime.h>
#include <hip/hip_bf16.h>

#define DM 512      // d_model
#define DI 1024     // d_inner
#define DSTATE 16
#define DTR 32      // dt_rank
#define NLAYER 8
#define BS 4
#define LL 256      // tokens per batch (F*NP)
#define MT 1024     // BS*LL total tokens
#define DPROJ 256
#define CL 32       // scan chunk length (timesteps staged in LDS)
#define NCH (LL/CL)

__device__ __forceinline__ float sigmoidf_(float x){ return 1.f/(1.f+__expf(-x)); }

// ---------------- patch embed: x[m,d] = sum_p ts[b, np*4+p] * ew[d,p] + eb[d]
__global__ __launch_bounds__(256) void embed_k(const float* __restrict__ ts,
    const float* __restrict__ ew, const float* __restrict__ eb, float* __restrict__ x){
  int idx = blockIdx.x*256 + threadIdx.x;     // MT*DM
  int m = idx >> 9, d = idx & 511;
  int b = m >> 8, np_ = m & 255;
  const float* t0 = ts + b*1024 + np_*4;
  float acc = eb[d];
  #pragma unroll
  for (int p=0;p<4;p++) acc = fmaf(t0[p], ew[d*4+p], acc);
  x[idx] = acc;
}

// ---------------- rmsnorm + write both normal and L-flipped copies
__global__ __launch_bounds__(256) void rmsnorm_k(const float* __restrict__ x,
    const float* __restrict__ nw, float* __restrict__ xn, float* __restrict__ xnf){
  int m = blockIdx.x, t = threadIdx.x;
  float2 v = *(const float2*)&x[(long)m*DM + t*2];
  float ss = v.x*v.x + v.y*v.y;
  ss += __shfl_down(ss,32); ss += __shfl_down(ss,16); ss += __shfl_down(ss,8);
  ss += __shfl_down(ss,4);  ss += __shfl_down(ss,2);  ss += __shfl_down(ss,1);
  __shared__ float ps[4];
  if ((t&63)==0) ps[t>>6] = ss;
  __syncthreads();
  float tot = ps[0]+ps[1]+ps[2]+ps[3];
  float rs = rsqrtf(tot*(1.f/DM) + 1e-5f);
  int b = m>>8, l = m&255, mf = (b<<8)+(255-l);
  float o0 = v.x*rs*nw[t*2], o1 = v.y*rs*nw[t*2+1];
  xn[(long)m*DM + t*2]  = o0; xn[(long)m*DM + t*2+1]  = o1;
  xnf[(long)mf*DM + t*2] = o0; xnf[(long)mf*DM + t*2+1] = o1;
}

// ---------------- generic C = A @ W^T   (A: MxK row-major w/ lda, W: NxK row-major)
// EPI: 0 = plain store, 1 = +bias, softplus, 2 = +bias, scatter to final output layout
template<int EPI>
__global__ __launch_bounds__(256) void gemm_nt(
    const float* __restrict__ A, int lda, long sA,
    const float* __restrict__ W, long sW,
    const float* __restrict__ bias, long sB,
    float* __restrict__ C, int ldc, long sC,
    int M, int N, int K)
{
  int z = blockIdx.z;
  A += z*sA; W += z*sW; C += z*sC;
  if (EPI==1) bias += z*sB;
  __shared__ float As[16][68];
  __shared__ float Ws[16][68];
  int tx = threadIdx.x, ty = threadIdx.y;
  int t = ty*16 + tx;
  int m0 = blockIdx.y*64, n0 = blockIdx.x*64;
  int lr = t>>2, lk = (t&3)*4;            // each thread loads a float4 of A and of W
  float acc[4][4] = {};
  for (int k0=0; k0<K; k0+=16){
    float4 va = *(const float4*)&A[(long)(m0+lr)*lda + k0 + lk];
    float4 vw = *(const float4*)&W[(long)(n0+lr)*K  + k0 + lk];
    As[lk][lr]=va.x; As[lk+1][lr]=va.y; As[lk+2][lr]=va.z; As[lk+3][lr]=va.w;
    Ws[lk][lr]=vw.x; Ws[lk+1][lr]=vw.y; Ws[lk+2][lr]=vw.z; Ws[lk+3][lr]=vw.w;
    __syncthreads();
    #pragma unroll
    for (int kk=0;kk<16;kk++){
      float a[4], bv[4];
      #pragma unroll
      for (int i=0;i<4;i++) a[i]  = As[kk][ty*4+i];
      #pragma unroll
      for (int j=0;j<4;j++) bv[j] = Ws[kk][tx*4+j];
      #pragma unroll
      for (int i=0;i<4;i++)
        #pragma unroll
        for (int j=0;j<4;j++)
          acc[i][j] = fmaf(a[i], bv[j], acc[i][j]);
    }
    __syncthreads();
  }
  #pragma unroll
  for (int i=0;i<4;i++){
    int m = m0 + ty*4 + i;
    #pragma unroll
    for (int j=0;j<4;j++){
      int n = n0 + tx*4 + j;
      float v = acc[i][j];
      if (EPI==1){ v += bias[n]; v = (v>20.f) ? v : log1pf(__expf(v)); }
      if (EPI==2){
        v += bias[n];
        int b = m>>8, np_ = m&255, p = n>>8, dp = n&255;
        C[((long)(b*1024 + np_*4 + p))*256 + dp] = v;
      } else {
        C[(long)m*ldc + n] = v;
      }
    }
  }
}

// ---------------- causal depthwise conv (taps=4) + bias + silu on u-half of xz
__global__ __launch_bounds__(256) void conv_silu_k(const float* __restrict__ xz,
    const float* __restrict__ cw, const float* __restrict__ cb, float* __restrict__ u){
  long idx = (long)blockIdx.x*256 + threadIdx.x;  // 2*MT*DI
  int e  = (int)(idx & (DI-1));
  int dm = (int)(idx >> 10);           // dir*MT + m
  int dir = dm >> 10;
  int m  = dm & (MT-1);
  int l  = m & (LL-1);
  const float* w = cw + ((long)dir*DI + e)*4;
  float acc = cb[dir*DI + e];
  const float* src = xz + (long)dm*2048 + e;   // u-half: cols [0,1024)
  #pragma unroll
  for (int j=0;j<4;j++){
    int ll = l - 3 + j;
    if (ll >= 0) acc = fmaf(w[j], src[(long)(j-3)*2048], acc);
  }
  u[idx] = acc * sigmoidf_(acc);
}

// ---------------- selective scan with chunked LDS staging
// block = 256 threads = (el 0..15) x (n 0..15); grid (64, B, 2)
__global__ __launch_bounds__(256) void scan_k(
    const float* __restrict__ delta, const float* __restrict__ u,
    const float* __restrict__ xz, const float* __restrict__ xdbl,
    const float* __restrict__ A_log, const float* __restrict__ Dp,
    float* __restrict__ yg)
{
  int t = threadIdx.x;
  int n = t & 15, el = t >> 4;
  int ec = blockIdx.x, b = blockIdx.y, dir = blockIdx.z;
  int e0 = ec*16;
  int e = e0 + el;
  float Av = -__expf(A_log[((long)dir*DI + e)*16 + n]);
  float Dv = Dp[dir*DI + e];
  long mbase = (long)dir*MT + b*LL;
  const float* dp_ = delta + mbase*DI;
  const float* up_ = u     + mbase*DI;
  const float* zp_ = xz    + mbase*2048 + 1024;
  const float* bc_ = xdbl  + mbase*64 + 32;
  float* yp_ = yg + mbase*DI;

  __shared__ float sB[2][CL][16];
  __shared__ float sC[2][CL][16];
  __shared__ float sd[2][CL][16];
  __shared__ float su[2][CL][16];
  __shared__ float sz[2][CL][16];
  __shared__ float sy[CL][16];

  // per-thread staging coordinates
  int lb  = t >> 3,        jb = (t & 7) * 4;          // BC: 256 x float4
  int tt  = t & 127;
  int ld_ = tt >> 2,       ed = (tt & 3) * 4;         // d/u/z: 128 x float4 each

  float4 pbc, pdu, pz;
  auto load_pre = [&](int c){
    long l0 = (long)c*CL;
    pbc = *(const float4*)&bc_[(l0+lb)*64 + jb];
    pdu = (t < 128) ? *(const float4*)&dp_[(l0+ld_)*DI + e0 + ed]
                    : *(const float4*)&up_[(l0+ld_)*DI + e0 + ed];
    if (t < 128) pz = *(const float4*)&zp_[(l0+ld_)*2048 + e0 + ed];
  };
  auto write_pre = [&](int buf){
    if (jb < 16) *(float4*)&sB[buf][lb][jb]    = pbc;
    else         *(float4*)&sC[buf][lb][jb-16] = pbc;
    if (t < 128) *(float4*)&sd[buf][ld_][ed] = pdu;
    else         *(float4*)&su[buf][ld_][ed] = pdu;
    if (t < 128) *(float4*)&sz[buf][ld_][ed] = pz;
  };

  load_pre(0);
  write_pre(0);
  load_pre(1);
  __syncthreads();

  float h = 0.f;
  for (int c = 0; c < NCH; ++c){
    int cur = c & 1;
    #pragma unroll 8
    for (int l = 0; l < CL; ++l){
      float dv = sd[cur][l][el];
      float uv = su[cur][l][el];
      float Bv = sB[cur][l][n];
      float Cv = sC[cur][l][n];
      float dA = __expf(dv*Av);
      h = fmaf(dA, h, dv*uv*Bv);
      float yc = h*Cv;
      yc += __shfl_xor(yc,1); yc += __shfl_xor(yc,2);
      yc += __shfl_xor(yc,4); yc += __shfl_xor(yc,8);
      if (n==0){
        float zv = sz[cur][l][el];
        sy[l][el] = (yc + uv*Dv) * (zv * sigmoidf_(zv));
      }
    }
    __syncthreads();   // sy complete; buf[cur] free
    if (c+1 < NCH){
      write_pre(cur^1);            // drains in-flight loads for chunk c+1
      if (c+2 < NCH) load_pre(c+2);
    }
    // bulk store y for chunk c
    if (t < 128){
      long l0 = (long)c*CL;
      *(float4*)&yp_[(l0+ld_)*DI + e0 + ed] = *(const float4*)&sy[ld_][ed];
    }
    __syncthreads();   // next buffer written; sy read out
  }
}

// ---------------- x = res + yf + flip(yb)
__global__ __launch_bounds__(256) void combine_k(float* __restrict__ x, const float* __restrict__ yout){
  int idx = blockIdx.x*256 + threadIdx.x;   // MT*DM/4
  int m = idx >> 7, c4 = idx & 127;
  int b = m>>8, l = m&255, mf = (b<<8)+(255-l);
  float4 r = ((const float4*)x)[idx];
  float4 f = ((const float4*)yout)[idx];
  float4 g = ((const float4*)(yout + (long)MT*DM))[(long)mf*128 + c4];
  r.x += f.x + g.x; r.y += f.y + g.y; r.z += f.z + g.z; r.w += f.w + g.w;
  ((float4*)x)[idx] = r;
}

extern "C" void kernel_launch(void* const* d_in, const int* in_sizes, int n_in,
                              void* d_out, int out_size, void* d_ws, size_t ws_size,
                              hipStream_t stream){
  const float* ts   = (const float*)d_in[0];
  // d_in[1] = mask (unused by reference)
  const float* ew   = (const float*)d_in[2];
  const float* eb   = (const float*)d_in[3];
  const float* nw   = (const float*)d_in[4];
  const float* inw  = (const float*)d_in[5];
  const float* cw   = (const float*)d_in[6];
  const float* cb   = (const float*)d_in[7];
  const float* xpw  = (const float*)d_in[8];
  const float* dtw  = (const float*)d_in[9];
  const float* dtb  = (const float*)d_in[10];
  const float* alog = (const float*)d_in[11];
  const float* dpp  = (const float*)d_in[12];
  const float* outw = (const float*)d_in[13];
  const float* pw   = (const float*)d_in[14];
  const float* pb   = (const float*)d_in[15];
  float* out = (float*)d_out;

  float* ws   = (float*)d_ws;
  float* x    = ws;                 // MT*DM              = 524288
  float* xn   = x    + 524288;      // 2*MT*DM (xn|xnf)   = 1048576
  float* xz   = xn   + 1048576;     // 2*MT*2048          = 4194304
  float* u    = xz   + 4194304;     // 2*MT*DI            = 2097152
  float* xdbl = u    + 2097152;     // 2*MT*64            = 131072
  float* delta= xdbl + 131072;      // 2*MT*DI            = 2097152
  float* yg   = delta+ 2097152;     // 2*MT*DI            = 2097152
  float* yout = yg   + 2097152;     // 2*MT*DM            = 1048576

  dim3 blk(256);
  dim3 gblk(16,16);

  embed_k<<<MT*DM/256, blk, 0, stream>>>(ts, ew, eb, x);

  for (int i=0;i<NLAYER;i++){
    rmsnorm_k<<<MT, blk, 0, stream>>>(x, nw + i*DM, xn, xn + 524288);
    // in_proj: (MT x 512) @ (2048 x 512)^T -> xz (MT x 2048), both dirs via z
    gemm_nt<0><<<dim3(2048/64, MT/64, 2), gblk, 0, stream>>>(
        xn, DM, 524288, inw + (long)i*2*2048*DM, (long)2048*DM,
        nullptr, 0, xz, 2048, (long)MT*2048, MT, 2048, DM);
    conv_silu_k<<<2*MT*DI/256, blk, 0, stream>>>(xz, cw + (long)i*2*DI*4, cb + i*2*DI, u);
    // x_dbl: (MT x 1024) @ (64 x 1024)^T
    gemm_nt<0><<<dim3(1, MT/64, 2), gblk, 0, stream>>>(
        u, DI, (long)MT*DI, xpw + (long)i*2*64*DI, (long)64*DI,
        nullptr, 0, xdbl, 64, (long)MT*64, MT, 64, DI);
    // delta = softplus(x_dbl[:, :32] @ (1024 x 32)^T + dt_b)
    gemm_nt<1><<<dim3(DI/64, MT/64, 2), gblk, 0, stream>>>(
        xdbl, 64, (long)MT*64, dtw + (long)i*2*DI*DTR, (long)DI*DTR,
        dtb + i*2*DI, DI, delta, DI, (long)MT*DI, MT, DI, DTR);
    scan_k<<<dim3(64, BS, 2), blk, 0, stream>>>(delta, u, xz, xdbl,
        alog + (long)i*2*DI*16, dpp + i*2*DI, yg);
    // out_proj: (MT x 1024) @ (512 x 1024)^T
    gemm_nt<0><<<dim3(DM/64, MT/64, 2), gblk, 0, stream>>>(
        yg, DI, (long)MT*DI, outw + (long)i*2*DM*DI, (long)DM*DI,
        nullptr, 0, yout, DM, (long)MT*DM, MT, DM, DI);
    combine_k<<<MT*DM/4/256, blk, 0, stream>>>(x, yout);
  }
  // final proj + bias + scatter into (B, S, F, D_PROJ) layout
  gemm_nt<2><<<dim3(1024/64, MT/64, 1), gblk, 0, stream>>>(
      x, DM, 0, pw, 0, pb, 0, out, 1024, 0, MT, 1024, DM);
}

// Round 4
// 1824.256 us; speedup vs baseline: 1.7074x; 1.1649x over previous
//
#include <hip/hip_runtime.h>
#include <hip/hip_bf16.h>

#define DM 512      // d_model
#define DI 1024     // d_inner
#define DSTATE 16
#define DTR 32      // dt_rank
#define NLAYER 8
#define BS 4
#define LL 256      // tokens per batch (F*NP)
#define MT 1024     // BS*LL total tokens
#define DPROJ 256
#define CL 32       // scan chunk length (timesteps staged in LDS)
#define NCH (LL/CL)

__device__ __forceinline__ float sigmoidf_(float x){ return 1.f/(1.f+__expf(-x)); }

// VALU-pipe 16-lane sum via DPP row rotations (no DS-pipe traffic)
template<int CTRL>
__device__ __forceinline__ float dpp_ror_add(float x){
  int y = __builtin_amdgcn_update_dpp(0, __float_as_int(x), CTRL, 0xF, 0xF, false);
  return x + __int_as_float(y);
}
__device__ __forceinline__ float sum16_dpp(float x){
  x = dpp_ror_add<0x128>(x);   // row_ror:8
  x = dpp_ror_add<0x124>(x);   // row_ror:4
  x = dpp_ror_add<0x122>(x);   // row_ror:2
  x = dpp_ror_add<0x121>(x);   // row_ror:1
  return x;
}

// ---------------- patch embed: x[m,d] = sum_p ts[b, np*4+p] * ew[d,p] + eb[d]
__global__ __launch_bounds__(256) void embed_k(const float* __restrict__ ts,
    const float* __restrict__ ew, const float* __restrict__ eb, float* __restrict__ x){
  int idx = blockIdx.x*256 + threadIdx.x;     // MT*DM
  int m = idx >> 9, d = idx & 511;
  int b = m >> 8, np_ = m & 255;
  const float* t0 = ts + b*1024 + np_*4;
  float acc = eb[d];
  #pragma unroll
  for (int p=0;p<4;p++) acc = fmaf(t0[p], ew[d*4+p], acc);
  x[idx] = acc;
}

// ---------------- rmsnorm + write both normal and L-flipped copies
__global__ __launch_bounds__(256) void rmsnorm_k(const float* __restrict__ x,
    const float* __restrict__ nw, float* __restrict__ xn, float* __restrict__ xnf){
  int m = blockIdx.x, t = threadIdx.x;
  float2 v = *(const float2*)&x[(long)m*DM + t*2];
  float ss = v.x*v.x + v.y*v.y;
  ss += __shfl_down(ss,32); ss += __shfl_down(ss,16); ss += __shfl_down(ss,8);
  ss += __shfl_down(ss,4);  ss += __shfl_down(ss,2);  ss += __shfl_down(ss,1);
  __shared__ float ps[4];
  if ((t&63)==0) ps[t>>6] = ss;
  __syncthreads();
  float tot = ps[0]+ps[1]+ps[2]+ps[3];
  float rs = rsqrtf(tot*(1.f/DM) + 1e-5f);
  int b = m>>8, l = m&255, mf = (b<<8)+(255-l);
  float o0 = v.x*rs*nw[t*2], o1 = v.y*rs*nw[t*2+1];
  xn[(long)m*DM + t*2]  = o0; xn[(long)m*DM + t*2+1]  = o1;
  xnf[(long)mf*DM + t*2] = o0; xnf[(long)mf*DM + t*2+1] = o1;
}

// ---------------- generic C = A @ W^T   (A: MxK row-major w/ lda, W: NxK row-major)
// EPI: 0 = plain store, 1 = +bias, softplus, 2 = +bias, scatter to final output layout
template<int EPI>
__global__ __launch_bounds__(256) void gemm_nt(
    const float* __restrict__ A, int lda, long sA,
    const float* __restrict__ W, long sW,
    const float* __restrict__ bias, long sB,
    float* __restrict__ C, int ldc, long sC,
    int M, int N, int K)
{
  int z = blockIdx.z;
  A += z*sA; W += z*sW; C += z*sC;
  if (EPI==1) bias += z*sB;
  __shared__ float As[16][68];
  __shared__ float Ws[16][68];
  int tx = threadIdx.x, ty = threadIdx.y;
  int t = ty*16 + tx;
  int m0 = blockIdx.y*64, n0 = blockIdx.x*64;
  int lr = t>>2, lk = (t&3)*4;            // each thread loads a float4 of A and of W
  float acc[4][4] = {};
  for (int k0=0; k0<K; k0+=16){
    float4 va = *(const float4*)&A[(long)(m0+lr)*lda + k0 + lk];
    float4 vw = *(const float4*)&W[(long)(n0+lr)*K  + k0 + lk];
    As[lk][lr]=va.x; As[lk+1][lr]=va.y; As[lk+2][lr]=va.z; As[lk+3][lr]=va.w;
    Ws[lk][lr]=vw.x; Ws[lk+1][lr]=vw.y; Ws[lk+2][lr]=vw.z; Ws[lk+3][lr]=vw.w;
    __syncthreads();
    #pragma unroll
    for (int kk=0;kk<16;kk++){
      float a[4], bv[4];
      #pragma unroll
      for (int i=0;i<4;i++) a[i]  = As[kk][ty*4+i];
      #pragma unroll
      for (int j=0;j<4;j++) bv[j] = Ws[kk][tx*4+j];
      #pragma unroll
      for (int i=0;i<4;i++)
        #pragma unroll
        for (int j=0;j<4;j++)
          acc[i][j] = fmaf(a[i], bv[j], acc[i][j]);
    }
    __syncthreads();
  }
  #pragma unroll
  for (int i=0;i<4;i++){
    int m = m0 + ty*4 + i;
    #pragma unroll
    for (int j=0;j<4;j++){
      int n = n0 + tx*4 + j;
      float v = acc[i][j];
      if (EPI==1){ v += bias[n]; v = (v>20.f) ? v : log1pf(__expf(v)); }
      if (EPI==2){
        v += bias[n];
        int b = m>>8, np_ = m&255, p = n>>8, dp = n&255;
        C[((long)(b*1024 + np_*4 + p))*256 + dp] = v;
      } else {
        C[(long)m*ldc + n] = v;
      }
    }
  }
}

// ---------------- causal depthwise conv (taps=4) + bias + silu on u-half of xz
__global__ __launch_bounds__(256) void conv_silu_k(const float* __restrict__ xz,
    const float* __restrict__ cw, const float* __restrict__ cb, float* __restrict__ u){
  long idx = (long)blockIdx.x*256 + threadIdx.x;  // 2*MT*DI
  int e  = (int)(idx & (DI-1));
  int dm = (int)(idx >> 10);           // dir*MT + m
  int dir = dm >> 10;
  int m  = dm & (MT-1);
  int l  = m & (LL-1);
  const float* w = cw + ((long)dir*DI + e)*4;
  float acc = cb[dir*DI + e];
  const float* src = xz + (long)dm*2048 + e;   // u-half: cols [0,1024)
  #pragma unroll
  for (int j=0;j<4;j++){
    int ll = l - 3 + j;
    if (ll >= 0) acc = fmaf(w[j], src[(long)(j-3)*2048], acc);
  }
  u[idx] = acc * sigmoidf_(acc);
}

// ---------------- selective scan, chunked LDS staging, DS-minimized inner loop
// block = 256 threads = (el 0..15) x (n 0..15); grid (64, B, 2)
__global__ __launch_bounds__(256) void scan_k(
    const float* __restrict__ delta, const float* __restrict__ u,
    const float* __restrict__ xz, const float* __restrict__ xdbl,
    const float* __restrict__ A_log, const float* __restrict__ Dp,
    float* __restrict__ yg)
{
  int t = threadIdx.x;
  int n = t & 15, el = t >> 4;
  int ec = blockIdx.x, b = blockIdx.y, dir = blockIdx.z;
  int e0 = ec*16;
  int e = e0 + el;
  float Av = -__expf(A_log[((long)dir*DI + e)*16 + n]);
  float Dv = Dp[dir*DI + e];
  long mbase = (long)dir*MT + b*LL;
  const float* dp_ = delta + mbase*DI;
  const float* up_ = u     + mbase*DI;
  const float* zp_ = xz    + mbase*2048 + 1024;
  const float* bc_ = xdbl  + mbase*64 + 32;
  float* yp_ = yg + mbase*DI;

  // paired layouts: per l, 32 floats = [d-row(16) | u-row(16)] and [B-row | C-row]
  __shared__ float sDU[2][CL][32];
  __shared__ float sBC[2][CL][32];
  __shared__ float sy[CL][16];

  // staging coordinates
  int lb  = t >> 3,        jb = (t & 7) * 4;          // BC: 256 lanes x float4
  int tt  = t & 127;
  int ld_ = tt >> 2,       ed = (tt & 3) * 4;         // d/u: 128 lanes x float4 each

  float4 pbc, pdu;
  auto load_pre = [&](int c){
    long l0 = (long)c*CL;
    pbc = *(const float4*)&bc_[(l0+lb)*64 + jb];
    pdu = (t < 128) ? *(const float4*)&dp_[(l0+ld_)*DI + e0 + ed]
                    : *(const float4*)&up_[(l0+ld_)*DI + e0 + ed];
  };
  auto write_pre = [&](int buf){
    if (jb < 16) *(float4*)&sBC[buf][lb][jb]    = pbc;
    else         *(float4*)&sBC[buf][lb][jb]    = pbc;   // jb>=16 lands in C-row naturally
    if (t < 128) *(float4*)&sDU[buf][ld_][ed]      = pdu;
    else         *(float4*)&sDU[buf][ld_][16+ed]   = pdu;
  };

  load_pre(0);
  write_pre(0);
  load_pre(1);
  __syncthreads();

  float h = 0.f;
  for (int c = 0; c < NCH; ++c){
    int cur = c & 1;
    // issue z load for this chunk now; consumed after compute (latency hidden)
    float4 zc;
    if (t < 128) zc = *(const float4*)&zp_[((long)c*CL + ld_)*2048 + e0 + ed];

    const float* du = &sDU[cur][0][el];
    const float* bc = &sBC[cur][0][n];
    #pragma unroll 8
    for (int l = 0; l < CL; ++l){
      float dv = du[l*32],     uv = du[l*32 + 16];
      float Bv = bc[l*32],     Cv = bc[l*32 + 16];
      float dA = __expf(dv*Av);
      h = fmaf(dA, h, dv*uv*Bv);
      float yc = sum16_dpp(h*Cv);
      if (n==0) sy[l][el] = yc + uv*Dv;
    }
    __syncthreads();   // sy complete; buf[cur] free
    if (c+1 < NCH){
      write_pre(cur^1);            // drains in-flight loads for chunk c+1
      if (c+2 < NCH) load_pre(c+2);
    }
    // bulk store y for chunk c with fused silu(z) gate
    if (t < 128){
      float4 y4 = *(const float4*)&sy[ld_][ed];
      y4.x *= zc.x * sigmoidf_(zc.x);
      y4.y *= zc.y * sigmoidf_(zc.y);
      y4.z *= zc.z * sigmoidf_(zc.z);
      y4.w *= zc.w * sigmoidf_(zc.w);
      *(float4*)&yp_[((long)c*CL + ld_)*DI + e0 + ed] = y4;
    }
    __syncthreads();   // next buffer staged; sy read out
  }
}

// ---------------- x = res + yf + flip(yb)
__global__ __launch_bounds__(256) void combine_k(float* __restrict__ x, const float* __restrict__ yout){
  int idx = blockIdx.x*256 + threadIdx.x;   // MT*DM/4
  int m = idx >> 7, c4 = idx & 127;
  int b = m>>8, l = m&255, mf = (b<<8)+(255-l);
  float4 r = ((const float4*)x)[idx];
  float4 f = ((const float4*)yout)[idx];
  float4 g = ((const float4*)(yout + (long)MT*DM))[(long)mf*128 + c4];
  r.x += f.x + g.x; r.y += f.y + g.y; r.z += f.z + g.z; r.w += f.w + g.w;
  ((float4*)x)[idx] = r;
}

extern "C" void kernel_launch(void* const* d_in, const int* in_sizes, int n_in,
                              void* d_out, int out_size, void* d_ws, size_t ws_size,
                              hipStream_t stream){
  const float* ts   = (const float*)d_in[0];
  // d_in[1] = mask (unused by reference)
  const float* ew   = (const float*)d_in[2];
  const float* eb   = (const float*)d_in[3];
  const float* nw   = (const float*)d_in[4];
  const float* inw  = (const float*)d_in[5];
  const float* cw   = (const float*)d_in[6];
  const float* cb   = (const float*)d_in[7];
  const float* xpw  = (const float*)d_in[8];
  const float* dtw  = (const float*)d_in[9];
  const float* dtb  = (const float*)d_in[10];
  const float* alog = (const float*)d_in[11];
  const float* dpp  = (const float*)d_in[12];
  const float* outw = (const float*)d_in[13];
  const float* pw   = (const float*)d_in[14];
  const float* pb   = (const float*)d_in[15];
  float* out = (float*)d_out;

  float* ws   = (float*)d_ws;
  float* x    = ws;                 // MT*DM              = 524288
  float* xn   = x    + 524288;      // 2*MT*DM (xn|xnf)   = 1048576
  float* xz   = xn   + 1048576;     // 2*MT*2048          = 4194304
  float* u    = xz   + 4194304;     // 2*MT*DI            = 2097152
  float* xdbl = u    + 2097152;     // 2*MT*64            = 131072
  float* delta= xdbl + 131072;      // 2*MT*DI            = 2097152
  float* yg   = delta+ 2097152;     // 2*MT*DI            = 2097152
  float* yout = yg   + 2097152;     // 2*MT*DM            = 1048576

  dim3 blk(256);
  dim3 gblk(16,16);

  embed_k<<<MT*DM/256, blk, 0, stream>>>(ts, ew, eb, x);

  for (int i=0;i<NLAYER;i++){
    rmsnorm_k<<<MT, blk, 0, stream>>>(x, nw + i*DM, xn, xn + 524288);
    // in_proj: (MT x 512) @ (2048 x 512)^T -> xz (MT x 2048), both dirs via z
    gemm_nt<0><<<dim3(2048/64, MT/64, 2), gblk, 0, stream>>>(
        xn, DM, 524288, inw + (long)i*2*2048*DM, (long)2048*DM,
        nullptr, 0, xz, 2048, (long)MT*2048, MT, 2048, DM);
    conv_silu_k<<<2*MT*DI/256, blk, 0, stream>>>(xz, cw + (long)i*2*DI*4, cb + i*2*DI, u);
    // x_dbl: (MT x 1024) @ (64 x 1024)^T
    gemm_nt<0><<<dim3(1, MT/64, 2), gblk, 0, stream>>>(
        u, DI, (long)MT*DI, xpw + (long)i*2*64*DI, (long)64*DI,
        nullptr, 0, xdbl, 64, (long)MT*64, MT, 64, DI);
    // delta = softplus(x_dbl[:, :32] @ (1024 x 32)^T + dt_b)
    gemm_nt<1><<<dim3(DI/64, MT/64, 2), gblk, 0, stream>>>(
        xdbl, 64, (long)MT*64, dtw + (long)i*2*DI*DTR, (long)DI*DTR,
        dtb + i*2*DI, DI, delta, DI, (long)MT*DI, MT, DI, DTR);
    scan_k<<<dim3(64, BS, 2), blk, 0, stream>>>(delta, u, xz, xdbl,
        alog + (long)i*2*DI*16, dpp + i*2*DI, yg);
    // out_proj: (MT x 1024) @ (512 x 1024)^T
    gemm_nt<0><<<dim3(DM/64, MT/64, 2), gblk, 0, stream>>>(
        yg, DI, (long)MT*DI, outw + (long)i*2*DM*DI, (long)DM*DI,
        nullptr, 0, yout, DM, (long)MT*DM, MT, DM, DI);
    combine_k<<<MT*DM/4/256, blk, 0, stream>>>(x, yout);
  }
  // final proj + bias + scatter into (B, S, F, D_PROJ) layout
  gemm_nt<2><<<dim3(1024/64, MT/64, 1), gblk, 0, stream>>>(
      x, DM, 0, pw, 0, pb, 0, out, 1024, 0, MT, 1024, DM);
}

// Round 5
// 1019.625 us; speedup vs baseline: 3.0547x; 1.7891x over previous
//
#include <hip/hip_runtime.h>
#include <hip/hip_bf16.h>

#define DM 512      // d_model
#define DI 1024     // d_inner
#define DSTATE 16
#define DTR 32      // dt_rank
#define NLAYER 8
#define BS 4
#define LL 256      // tokens per batch (F*NP)
#define MT 1024     // BS*LL total tokens
#define DPROJ 256
#define CL 32       // scan chunk length
#define NCH (LL/CL)

typedef unsigned short u16;
typedef __attribute__((ext_vector_type(8))) short short8;
typedef __attribute__((ext_vector_type(4))) float f32x4;

__device__ __forceinline__ float sigmoidf_(float x){ return 1.f/(1.f+__expf(-x)); }

// fp32 -> bf16 round-to-nearest-even (finite inputs)
__device__ __forceinline__ u16 f2bf(float f){
  unsigned u = __float_as_uint(f);
  u = (u + 0x7FFF + ((u>>16)&1)) >> 16;
  return (u16)u;
}

// VALU-pipe 16-lane sum via DPP row rotations
template<int CTRL>
__device__ __forceinline__ float dpp_ror_add(float x){
  int y = __builtin_amdgcn_update_dpp(0, __float_as_int(x), CTRL, 0xF, 0xF, false);
  return x + __int_as_float(y);
}
__device__ __forceinline__ float sum16_dpp(float x){
  x = dpp_ror_add<0x128>(x);
  x = dpp_ror_add<0x124>(x);
  x = dpp_ror_add<0x122>(x);
  x = dpp_ror_add<0x121>(x);
  return x;
}

// ---------------- patch embed
__global__ __launch_bounds__(256) void embed_k(const float* __restrict__ ts,
    const float* __restrict__ ew, const float* __restrict__ eb, float* __restrict__ x){
  int idx = blockIdx.x*256 + threadIdx.x;     // MT*DM
  int m = idx >> 9, d = idx & 511;
  int b = m >> 8, np_ = m & 255;
  const float* t0 = ts + b*1024 + np_*4;
  float acc = eb[d];
  #pragma unroll
  for (int p=0;p<4;p++) acc = fmaf(t0[p], ew[d*4+p], acc);
  x[idx] = acc;
}

// ---------------- rmsnorm -> bf16 normal + flipped copies
__global__ __launch_bounds__(256) void rmsnorm_k(const float* __restrict__ x,
    const float* __restrict__ nw, u16* __restrict__ xnbf, u16* __restrict__ xnfbf){
  int m = blockIdx.x, t = threadIdx.x;
  float2 v = *(const float2*)&x[(long)m*DM + t*2];
  float ss = v.x*v.x + v.y*v.y;
  ss += __shfl_down(ss,32); ss += __shfl_down(ss,16); ss += __shfl_down(ss,8);
  ss += __shfl_down(ss,4);  ss += __shfl_down(ss,2);  ss += __shfl_down(ss,1);
  __shared__ float ps[4];
  if ((t&63)==0) ps[t>>6] = ss;
  __syncthreads();
  float tot = ps[0]+ps[1]+ps[2]+ps[3];
  float rs = rsqrtf(tot*(1.f/DM) + 1e-5f);
  int b = m>>8, l = m&255, mf = (b<<8)+(255-l);
  ushort2 o; o.x = f2bf(v.x*rs*nw[t*2]); o.y = f2bf(v.y*rs*nw[t*2+1]);
  *(ushort2*)&xnbf [(long)m *DM + t*2] = o;
  *(ushort2*)&xnfbf[(long)mf*DM + t*2] = o;
}

// ---------------- generic fp32->bf16 cast (float4 granularity)
__global__ __launch_bounds__(256) void cast4_k(const float* __restrict__ in,
    u16* __restrict__ o, int n4){
  int t = blockIdx.x*256 + threadIdx.x;
  if (t >= n4) return;
  float4 v = ((const float4*)in)[t];
  ushort4 r; r.x=f2bf(v.x); r.y=f2bf(v.y); r.z=f2bf(v.z); r.w=f2bf(v.w);
  ((ushort4*)o)[t] = r;
}

// ---------------- per-layer weight cast: in_w | out_w | xproj_w -> one bf16 buffer
__global__ __launch_bounds__(256) void wcast_k(const float* __restrict__ w_in,
    const float* __restrict__ w_out, const float* __restrict__ w_xp, u16* __restrict__ dst){
  int t = blockIdx.x*256 + threadIdx.x;   // 819200 float4s
  const float* src; int o4;
  if (t < 524288)      { src = w_in;  o4 = t; }
  else if (t < 786432) { src = w_out; o4 = t - 524288; }
  else                 { src = w_xp;  o4 = t - 786432; }
  float4 v = ((const float4*)src)[o4];
  ushort4 r; r.x=f2bf(v.x); r.y=f2bf(v.y); r.z=f2bf(v.z); r.w=f2bf(v.w);
  ((ushort4*)dst)[t] = r;
}

// ---------------- bf16 MFMA GEMM: C = A @ W^T
// A: (M,K) bf16 row-major; W: (N,K) bf16 row-major; C fp32.
// 256 threads = 4 waves (2x2). LDS layout [kc][row][8] -> 16B-stride lanes.
// SPLITK>1: z encodes dir*SPLITK+kc, partials to C + z*M*N.
// EPI: 0 plain, 2 final scatter+bias.
template<int BM,int BN,int SPLITK,int EPI>
__global__ __launch_bounds__(256) void mfma_nt(
    const u16* __restrict__ A, int lda, long sA,
    const u16* __restrict__ W, int ldw, long sW,
    const float* __restrict__ bias,
    float* __restrict__ C, int ldc, long sC,
    int M, int N, int K)
{
  constexpr int WM = BM/2, WN = BN/2;
  constexpr int MI = WM/16, NI = WN/16;
  int z = blockIdx.z;
  int dir = z / SPLITK, kc = z % SPLITK;
  int Klen = K / SPLITK;
  int kbase = kc * Klen;
  A += (long)dir * sA;
  W += (long)dir * sW;
  if (SPLITK > 1) C += (long)z * M * N; else C += (long)dir * sC;

  __shared__ u16 Al[BM*32];
  __shared__ u16 Wl[BN*32];
  int tid = threadIdx.x;
  int lane = tid & 63;
  int wave = tid >> 6;
  int wm0 = (wave>>1)*WM, wn0 = (wave&1)*WN;
  int m0 = blockIdx.y*BM, n0 = blockIdx.x*BN;
  int l16 = lane>>4, l15 = lane&15;

  f32x4 acc[MI][NI] = {};

  for (int k0=0; k0<Klen; k0+=32){
    #pragma unroll
    for (int it=0; it<BM*4/256; ++it){
      int ch = it*256 + tid;
      int row = ch % BM, kk = ch / BM;
      const u16* g = A + (long)(m0+row)*lda + kbase + k0 + kk*8;
      __builtin_amdgcn_global_load_lds(
          (const __attribute__((address_space(1))) void*)g,
          (__attribute__((address_space(3))) void*)(Al + ch*8), 16, 0, 0);
    }
    #pragma unroll
    for (int it=0; it<BN*4/256; ++it){
      int ch = it*256 + tid;
      int row = ch % BN, kk = ch / BN;
      const u16* g = W + (long)(n0+row)*ldw + kbase + k0 + kk*8;
      __builtin_amdgcn_global_load_lds(
          (const __attribute__((address_space(1))) void*)g,
          (__attribute__((address_space(3))) void*)(Wl + ch*8), 16, 0, 0);
    }
    __syncthreads();
    short8 a[MI], b[NI];
    #pragma unroll
    for (int i=0;i<MI;i++)
      a[i] = *(const short8*)&Al[(l16*BM + wm0 + i*16 + l15)*8];
    #pragma unroll
    for (int j=0;j<NI;j++)
      b[j] = *(const short8*)&Wl[(l16*BN + wn0 + j*16 + l15)*8];
    #pragma unroll
    for (int i=0;i<MI;i++)
      #pragma unroll
      for (int j=0;j<NI;j++)
        acc[i][j] = __builtin_amdgcn_mfma_f32_16x16x32_bf16(a[i], b[j], acc[i][j], 0,0,0);
    __syncthreads();
  }
  #pragma unroll
  for (int i=0;i<MI;i++){
    #pragma unroll
    for (int j=0;j<NI;j++){
      #pragma unroll
      for (int r=0;r<4;r++){
        int m = m0 + wm0 + i*16 + l16*4 + r;
        int n = n0 + wn0 + j*16 + l15;
        float v = acc[i][j][r];
        if (EPI==2){
          v += bias[n];
          int bb = m>>8, np_ = m&255, p = n>>8, dp = n&255;
          C[((long)(bb*1024 + np_*4 + p))*256 + dp] = v;
        } else {
          C[(long)m*ldc + n] = v;
        }
      }
    }
  }
}

// ---------------- split-K reduce for xproj: xdbl[d][m][64] = sum_kc parts
__global__ __launch_bounds__(256) void xreduce_k(const float* __restrict__ part,
    float* __restrict__ xdbl){
  int idx = blockIdx.x*256 + threadIdx.x;   // 131072
  int d = idx >> 16, off = idx & 65535;
  float s = 0.f;
  #pragma unroll
  for (int kc=0; kc<8; ++kc) s += part[((d*8+kc)<<16) + off];
  xdbl[idx] = s;
}

// ---------------- fp32 GEMM kept only for dt (K=32): +bias, softplus
template<int EPI>
__global__ __launch_bounds__(256) void gemm_nt(
    const float* __restrict__ A, int lda, long sA,
    const float* __restrict__ W, long sW,
    const float* __restrict__ bias, long sB,
    float* __restrict__ C, int ldc, long sC,
    int M, int N, int K)
{
  int z = blockIdx.z;
  A += z*sA; W += z*sW; C += z*sC;
  if (EPI==1) bias += z*sB;
  __shared__ float As[16][68];
  __shared__ float Ws[16][68];
  int tx = threadIdx.x, ty = threadIdx.y;
  int t = ty*16 + tx;
  int m0 = blockIdx.y*64, n0 = blockIdx.x*64;
  int lr = t>>2, lk = (t&3)*4;
  float acc[4][4] = {};
  for (int k0=0; k0<K; k0+=16){
    float4 va = *(const float4*)&A[(long)(m0+lr)*lda + k0 + lk];
    float4 vw = *(const float4*)&W[(long)(n0+lr)*K  + k0 + lk];
    As[lk][lr]=va.x; As[lk+1][lr]=va.y; As[lk+2][lr]=va.z; As[lk+3][lr]=va.w;
    Ws[lk][lr]=vw.x; Ws[lk+1][lr]=vw.y; Ws[lk+2][lr]=vw.z; Ws[lk+3][lr]=vw.w;
    __syncthreads();
    #pragma unroll
    for (int kk=0;kk<16;kk++){
      float a[4], bv[4];
      #pragma unroll
      for (int i=0;i<4;i++) a[i]  = As[kk][ty*4+i];
      #pragma unroll
      for (int j=0;j<4;j++) bv[j] = Ws[kk][tx*4+j];
      #pragma unroll
      for (int i=0;i<4;i++)
        #pragma unroll
        for (int j=0;j<4;j++)
          acc[i][j] = fmaf(a[i], bv[j], acc[i][j]);
    }
    __syncthreads();
  }
  #pragma unroll
  for (int i=0;i<4;i++){
    int m = m0 + ty*4 + i;
    #pragma unroll
    for (int j=0;j<4;j++){
      int n = n0 + tx*4 + j;
      float v = acc[i][j];
      if (EPI==1){ v += bias[n]; v = (v>20.f) ? v : log1pf(__expf(v)); }
      C[(long)m*ldc + n] = v;
    }
  }
}

// ---------------- causal depthwise conv + bias + silu; writes fp32 u and bf16 u
__global__ __launch_bounds__(256) void conv_silu_k(const float* __restrict__ xz,
    const float* __restrict__ cw, const float* __restrict__ cb,
    float* __restrict__ u, u16* __restrict__ ubf){
  long idx = (long)blockIdx.x*256 + threadIdx.x;  // 2*MT*DI
  int e  = (int)(idx & (DI-1));
  int dm = (int)(idx >> 10);
  int dir = dm >> 10;
  int m  = dm & (MT-1);
  int l  = m & (LL-1);
  const float* w = cw + ((long)dir*DI + e)*4;
  float acc = cb[dir*DI + e];
  const float* src = xz + (long)dm*2048 + e;
  #pragma unroll
  for (int j=0;j<4;j++){
    int ll = l - 3 + j;
    if (ll >= 0) acc = fmaf(w[j], src[(long)(j-3)*2048], acc);
  }
  float v = acc * sigmoidf_(acc);
  u[idx] = v;
  ubf[idx] = f2bf(v);
}

// ---------------- selective scan; epilogue writes gated y as bf16
__global__ __launch_bounds__(256) void scan_k(
    const float* __restrict__ delta, const float* __restrict__ u,
    const float* __restrict__ xz, const float* __restrict__ xdbl,
    const float* __restrict__ A_log, const float* __restrict__ Dp,
    u16* __restrict__ ygbf)
{
  int t = threadIdx.x;
  int n = t & 15, el = t >> 4;
  int ec = blockIdx.x, b = blockIdx.y, dir = blockIdx.z;
  int e0 = ec*16;
  int e = e0 + el;
  float Av = -__expf(A_log[((long)dir*DI + e)*16 + n]);
  float Dv = Dp[dir*DI + e];
  long mbase = (long)dir*MT + b*LL;
  const float* dp_ = delta + mbase*DI;
  const float* up_ = u     + mbase*DI;
  const float* zp_ = xz    + mbase*2048 + 1024;
  const float* bc_ = xdbl  + mbase*64 + 32;
  u16* yp_ = ygbf + mbase*DI;

  __shared__ float sDU[2][CL][32];
  __shared__ float sBC[2][CL][32];
  __shared__ float sy[CL][16];

  int lb  = t >> 3,        jb = (t & 7) * 4;
  int tt  = t & 127;
  int ld_ = tt >> 2,       ed = (tt & 3) * 4;

  float4 pbc, pdu;
  auto load_pre = [&](int c){
    long l0 = (long)c*CL;
    pbc = *(const float4*)&bc_[(l0+lb)*64 + jb];
    pdu = (t < 128) ? *(const float4*)&dp_[(l0+ld_)*DI + e0 + ed]
                    : *(const float4*)&up_[(l0+ld_)*DI + e0 + ed];
  };
  auto write_pre = [&](int buf){
    *(float4*)&sBC[buf][lb][jb] = pbc;
    if (t < 128) *(float4*)&sDU[buf][ld_][ed]      = pdu;
    else         *(float4*)&sDU[buf][ld_][16+ed]   = pdu;
  };

  load_pre(0);
  write_pre(0);
  load_pre(1);
  __syncthreads();

  float h = 0.f;
  for (int c = 0; c < NCH; ++c){
    int cur = c & 1;
    float4 zc;
    if (t < 128) zc = *(const float4*)&zp_[((long)c*CL + ld_)*2048 + e0 + ed];

    const float* du = &sDU[cur][0][el];
    const float* bc = &sBC[cur][0][n];
    #pragma unroll 8
    for (int l = 0; l < CL; ++l){
      float dv = du[l*32],     uv = du[l*32 + 16];
      float Bv = bc[l*32],     Cv = bc[l*32 + 16];
      float dA = __expf(dv*Av);
      h = fmaf(dA, h, dv*uv*Bv);
      float yc = sum16_dpp(h*Cv);
      if (n==0) sy[l][el] = yc + uv*Dv;
    }
    __syncthreads();
    if (c+1 < NCH){
      write_pre(cur^1);
      if (c+2 < NCH) load_pre(c+2);
    }
    if (t < 128){
      float4 y4 = *(const float4*)&sy[ld_][ed];
      float gx = zc.x*sigmoidf_(zc.x), gy = zc.y*sigmoidf_(zc.y);
      float gz = zc.z*sigmoidf_(zc.z), gw = zc.w*sigmoidf_(zc.w);
      ushort4 o; o.x=f2bf(y4.x*gx); o.y=f2bf(y4.y*gy); o.z=f2bf(y4.z*gz); o.w=f2bf(y4.w*gw);
      *(ushort4*)&yp_[((long)c*CL + ld_)*DI + e0 + ed] = o;
    }
    __syncthreads();
  }
}

// ---------------- x = res + yf + flip(yb)
__global__ __launch_bounds__(256) void combine_k(float* __restrict__ x, const float* __restrict__ yout){
  int idx = blockIdx.x*256 + threadIdx.x;   // MT*DM/4
  int m = idx >> 7, c4 = idx & 127;
  int b = m>>8, l = m&255, mf = (b<<8)+(255-l);
  float4 r = ((const float4*)x)[idx];
  float4 f = ((const float4*)yout)[idx];
  float4 g = ((const float4*)(yout + (long)MT*DM))[(long)mf*128 + c4];
  r.x += f.x + g.x; r.y += f.y + g.y; r.z += f.z + g.z; r.w += f.w + g.w;
  ((float4*)x)[idx] = r;
}

extern "C" void kernel_launch(void* const* d_in, const int* in_sizes, int n_in,
                              void* d_out, int out_size, void* d_ws, size_t ws_size,
                              hipStream_t stream){
  const float* ts   = (const float*)d_in[0];
  const float* ew   = (const float*)d_in[2];
  const float* eb   = (const float*)d_in[3];
  const float* nw   = (const float*)d_in[4];
  const float* inw  = (const float*)d_in[5];
  const float* cw   = (const float*)d_in[6];
  const float* cb   = (const float*)d_in[7];
  const float* xpw  = (const float*)d_in[8];
  const float* dtw  = (const float*)d_in[9];
  const float* dtb  = (const float*)d_in[10];
  const float* alog = (const float*)d_in[11];
  const float* dpp  = (const float*)d_in[12];
  const float* outw = (const float*)d_in[13];
  const float* pw   = (const float*)d_in[14];
  const float* pb   = (const float*)d_in[15];
  float* out = (float*)d_out;

  float* ws   = (float*)d_ws;
  float* x    = ws;                  // 524288
  float* xz   = ws + 524288;         // 4194304
  float* u    = ws + 4718592;        // 2097152
  float* xdbl = ws + 6815744;        // 131072
  float* delta= ws + 6946816;        // 2097152
  float* yout = ws + 9043968;        // 1048576
  float* xpart= ws + 10092544;       // 1048576 (2*8*1024*64)
  u16* ub     = (u16*)(ws + 11141120);
  u16* xn_bf  = ub;                  // 1048576 (both dirs)
  u16* u_bf   = ub + 1048576;        // 2097152
  u16* yg_bf  = ub + 3145728;        // 2097152
  u16* x_bf   = ub + 5242880;        // 524288
  u16* wbf    = ub + 5767168;        // 3276800 = in|out|xp
  u16* pj_bf  = ub + 9043968;        // 524288
  u16* wbf_in = wbf;
  u16* wbf_out= wbf + 2097152;
  u16* wbf_xp = wbf + 3145728;

  dim3 blk(256);
  dim3 gblk(16,16);

  embed_k<<<MT*DM/256, blk, 0, stream>>>(ts, ew, eb, x);
  cast4_k<<<512, blk, 0, stream>>>(pw, pj_bf, 131072);

  for (int i=0;i<NLAYER;i++){
    rmsnorm_k<<<MT, blk, 0, stream>>>(x, nw + i*DM, xn_bf, xn_bf + MT*DM);
    wcast_k<<<3200, blk, 0, stream>>>(inw + (long)i*2*2048*DM,
        outw + (long)i*2*DM*DI, xpw + (long)i*2*64*DI, wbf);
    // in_proj: (1024x512)@(2048x512)^T -> xz fp32, per dir
    mfma_nt<128,128,1,0><<<dim3(16,8,2), blk, 0, stream>>>(
        xn_bf, DM, (long)MT*DM, wbf_in, DM, (long)2048*DM,
        nullptr, xz, 2048, (long)MT*2048, MT, 2048, DM);
    conv_silu_k<<<2*MT*DI/256, blk, 0, stream>>>(xz, cw + (long)i*2*DI*4, cb + i*2*DI, u, u_bf);
    // xproj: (1024x1024)@(64x1024)^T split-K=8 -> partials -> xdbl
    mfma_nt<128,64,8,0><<<dim3(1,8,16), blk, 0, stream>>>(
        u_bf, DI, (long)MT*DI, wbf_xp, DI, (long)64*DI,
        nullptr, xpart, 64, 0, MT, 64, DI);
    xreduce_k<<<512, blk, 0, stream>>>(xpart, xdbl);
    // delta = softplus(xdbl[:,:32] @ dt_w^T + dt_b)   (fp32)
    gemm_nt<1><<<dim3(DI/64, MT/64, 2), gblk, 0, stream>>>(
        xdbl, 64, (long)MT*64, dtw + (long)i*2*DI*DTR, (long)DI*DTR,
        dtb + i*2*DI, DI, delta, DI, (long)MT*DI, MT, DI, DTR);
    scan_k<<<dim3(64, BS, 2), blk, 0, stream>>>(delta, u, xz, xdbl,
        alog + (long)i*2*DI*16, dpp + i*2*DI, yg_bf);
    // out_proj: (1024x1024)@(512x1024)^T -> yout fp32
    mfma_nt<128,64,1,0><<<dim3(8,8,2), blk, 0, stream>>>(
        yg_bf, DI, (long)MT*DI, wbf_out, DI, (long)DM*DI,
        nullptr, yout, DM, (long)MT*DM, MT, DM, DI);
    combine_k<<<MT*DM/4/256, blk, 0, stream>>>(x, yout);
  }
  cast4_k<<<512, blk, 0, stream>>>(x, x_bf, 131072);
  // final proj + bias + scatter
  mfma_nt<128,64,1,2><<<dim3(16,8,1), blk, 0, stream>>>(
      x_bf, DM, 0, pj_bf, DM, 0, pb, out, 1024, 0, MT, 1024, DM);
}